// Round 4
// baseline (317.822 us; speedup 1.0000x reference)
//
#include <hip/hip_runtime.h>

// B=16, L=2048, K=24, D=64
typedef _Float16 f16;
typedef _Float16 f16x4 __attribute__((ext_vector_type(4)));
typedef _Float16 f16x8 __attribute__((ext_vector_type(8)));
typedef float f32x4 __attribute__((ext_vector_type(4)));

__device__ __forceinline__ void gl_lds16(const void* g, void* l) {
  __builtin_amdgcn_global_load_lds(
      (__attribute__((address_space(1))) unsigned int*)(g),
      (__attribute__((address_space(3))) unsigned int*)(l), 16, 0, 0);
}

// ---- k_pre0: ALL independent precompute arms in launch #1 (728 blocks).
//   blk 0..255:   uin conversion (pre-swizzled f16 planes for k_w)
//   blk 256..279: phiT[k][e][d] = (f16) m_phi[(k*64+d)*64+e]
//   blk 280..663: Dpre phase-replicated Toeplitz tables
//   blk 664..727: zero out[]
__global__ __launch_bounds__(256) void k_pre0(const float* __restrict__ in,
                                              const float* __restrict__ m_phi,
                                              const float* __restrict__ ev,
                                              const float* __restrict__ evec,
                                              f16* __restrict__ phiT,
                                              f16* __restrict__ uin,
                                              f16* __restrict__ Dpre,
                                              float* __restrict__ out) {
  __shared__ float esm[256];
  int blk = blockIdx.x;
  int tid = threadIdx.x;
  if (blk < 256) {  // ---- uin conversion (one 128-s x 64-d plane per block)
    int b = blk >> 4, s0 = (blk & 15) * 128;
    f16* up = uin + (size_t)blk * 8192;
#pragma unroll
    for (int v = 0; v < 4; ++v) {
      int flat = v * 256 + tid;
      int row = flat >> 3, cl = flat & 7, cg = cl ^ (row & 7);
      const float* g = in + ((size_t)(b * 2048 + s0 + row)) * 64 + cg * 8;
      float4 u0 = *(const float4*)g;
      float4 u1 = *(const float4*)(g + 4);
      f16x8 h;
      h[0] = (f16)u0.x; h[1] = (f16)u0.y; h[2] = (f16)u0.z; h[3] = (f16)u0.w;
      h[4] = (f16)u1.x; h[5] = (f16)u1.y; h[6] = (f16)u1.z; h[7] = (f16)u1.w;
      *(f16x8*)&up[flat * 8] = h;
    }
    return;
  }
  if (blk < 280) {  // ---- phiT transpose
    int k = blk - 256;
    for (int idx = tid; idx < 4096; idx += 256) {
      int e = idx >> 6, d = idx & 63;
      phiT[k * 4096 + idx] = (f16)m_phi[(k * 64 + d) * 64 + e];
    }
    return;
  }
  if (blk < 664) {  // ---- Dpre blocks (384): D[p][y]=esm[254-p-y], pad 2560
    int a = blk - 280;
    int diag = a / 24, k = a % 24;
    float s4 = sqrtf(sqrtf(ev[k]));
    int base = diag * 128 - 127;
    if (tid < 255) {
      int v = base + tid;
      esm[tid] = (v >= 0) ? evec[v * 24 + k] * s4 : 0.0f;
    }
    __syncthreads();
    f16* plane = Dpre + (size_t)(diag * 24 + k) * 2560;
    for (int i = tid; i < 2560; i += 256) {
      float val = 0.f;
      if (i < 2112) {
        int p = i / 264, y = i - p * 264;
        int g = 254 - p - y;
        if (g >= 0) val = esm[g];
      }
      plane[i] = (f16)val;
    }
    return;
  }
  // ---- zero-out blocks: 64 blocks x 32768 floats
  float4* o = (float4*)(out + (size_t)(blk - 664) * 32768);
  float4 z4 = {0.f, 0.f, 0.f, 0.f};
#pragma unroll
  for (int i = 0; i < 32; ++i) o[i * 256 + tid] = z4;
}

// ---- k_w: W2T[b][k][e][s] = sum_d in[b][s][d] * m_phi[k*64+d][e]  (f16 out)
// [R15 proven version — unchanged]
__global__ __launch_bounds__(256) void k_w(const f16* __restrict__ uin,
                                           const f16* __restrict__ phiT,
                                           f16* __restrict__ W2T) {
  __shared__ __align__(16) f16 Ubuf[8320];
  __shared__ __align__(16) f16 Psm[64 * 64];
  int wblk = blockIdx.x;
  int s0 = (wblk & 15) * 128;
  int b = (wblk >> 4) & 15;
  int kg = wblk >> 8;  // 0..5
  int tid = threadIdx.x, lane = tid & 63, wv = tid >> 6;
  const f16* up = uin + (size_t)(wblk & 255) * 8192;
  // U stage: contiguous gl_lds (uin pre-swizzled by k_pre0)
#pragma unroll
  for (int v = 0; v < 4; ++v)
    gl_lds16(up + (size_t)(v * 256 + tid) * 8, &Ubuf[(v * 256 + wv * 64) * 8]);
  // P(k0) stage in the same vmcnt group
  {
    int k0 = kg * 4;
#pragma unroll
    for (int v = 0; v < 2; ++v) {
      int flat = v * 256 + tid;
      int row = flat >> 3, cl = flat & 7, cg = cl ^ (row & 7);
      gl_lds16(phiT + (size_t)k0 * 4096 + row * 64 + cg * 8,
               &Psm[(v * 256 + wv * 64) * 8]);
    }
  }
  __syncthreads();  // U + P0 resident
  int wm = wv * 32;
  f16x8 af[2][2];
#pragma unroll
  for (int ks = 0; ks < 2; ++ks)
#pragma unroll
    for (int x = 0; x < 2; ++x) {
      int m = wm + x * 16 + (lane & 15);
      int ch = (ks * 4 + (lane >> 4)) ^ (m & 7);
      af[ks][x] = *(const f16x8*)&Ubuf[m * 64 + ch * 8];
    }
  for (int ki = 0; ki < 4; ++ki) {
    int k = kg * 4 + ki;
    f32x4 zero = {0.f, 0.f, 0.f, 0.f};
    f32x4 acc[2][4];
#pragma unroll
    for (int x = 0; x < 2; ++x)
#pragma unroll
      for (int y = 0; y < 4; ++y) acc[x][y] = zero;
#pragma unroll
    for (int ks = 0; ks < 2; ++ks) {
      f16x8 bf[4];
#pragma unroll
      for (int y = 0; y < 4; ++y) {
        int n = y * 16 + (lane & 15);
        int ch = (ks * 4 + (lane >> 4)) ^ (n & 7);
        bf[y] = *(const f16x8*)&Psm[n * 64 + ch * 8];
      }
#pragma unroll
      for (int x = 0; x < 2; ++x)
#pragma unroll
        for (int y = 0; y < 4; ++y)
          acc[x][y] = __builtin_amdgcn_mfma_f32_16x16x32_f16(af[ks][x], bf[y], acc[x][y], 0, 0, 0);
    }
    __syncthreads();  // Psm reads + (iter0) af Ubuf reads done everywhere
    // transpose C (128 sigma x 64 e) into Ubuf as Csm[e][sigma], stride 130
#pragma unroll
    for (int x = 0; x < 2; ++x)
#pragma unroll
      for (int y = 0; y < 4; ++y) {
        int e = y * 16 + (lane & 15);
        int sg = wm + x * 16 + ((lane >> 4) << 2);
        f16x4 pk;
        pk[0] = (f16)acc[x][y][0]; pk[1] = (f16)acc[x][y][1];
        pk[2] = (f16)acc[x][y][2]; pk[3] = (f16)acc[x][y][3];
        *(f16x4*)&Ubuf[e * 130 + sg] = pk;
      }
    if (ki < 3) {  // prefetch next P (Psm safe to overwrite after sync above)
      int kn = k + 1;
#pragma unroll
      for (int v = 0; v < 2; ++v) {
        int flat = v * 256 + tid;
        int row = flat >> 3, cl = flat & 7, cg = cl ^ (row & 7);
        gl_lds16(phiT + (size_t)kn * 4096 + row * 64 + cg * 8,
                 &Psm[(v * 256 + wv * 64) * 8]);
      }
    }
    __syncthreads();  // Csm visible; P(kn) drained (implicit vmcnt(0))
    // coalesced stores: 1024 chunks of 16B; 16 lanes cover 256B of one e-row
#pragma unroll
    for (int pass = 0; pass < 4; ++pass) {
      int g = pass * 256 + tid;
      int e = g >> 4, ch = g & 15;
      f16x8 val = *(const f16x8*)&Ubuf[e * 130 + ch * 8];
      *(f16x8*)&W2T[((size_t)((b * 24 + k) * 64 + e)) * 2048 + s0 + ch * 8] = val;
    }
  }
}

// ---- k_main: causal block-Toeplitz GEMM, 128x128 tiles.
// R19 "dual-diag": key observation — for fixed (nt, st), EVERY diagonal
// reads the SAME B panels; only the 5 KB D table differs. The R15 grid
// re-staged the same 32 KB B tile up to 16x. Here each block owns a
// diag-PAIR {2dp, 2dp+1} for one (nt,st): stage B once per k, two D
// tables, 128 MFMA/wave per k-step -> 2x arithmetic intensity per staged
// byte. R15's plain 2-barrier schedule kept verbatim (R16-R18 measured:
// source-level pipelining on this structure only regresses).
// Grid (8,72) = 576 blocks, all co-resident at 3 blocks/CU (42 KB LDS).
// Odd-count st: last pair is a singleton — diag1 clamped to diag0, its
// (duplicate) tile computed and discarded => uniform work per block.
__global__ __launch_bounds__(256, 3) void k_main(const f16* __restrict__ Dpre,
                                                 const f16* __restrict__ W2T,
                                                 float* __restrict__ out) {
  __shared__ __align__(16) f16 Bsm[128 * 128];  // 32 KB
  __shared__ __align__(16) f16 Dsm[2][2560];    // 10 KB
  int nt = blockIdx.x;
  int p = blockIdx.y;
  // decode p -> (st, dp): st has ceil((16-st)/2) = (17-st)>>1 pairs
  int st = 0, off = 0;
  while (off + ((17 - st) >> 1) <= p) { off += (17 - st) >> 1; ++st; }
  int dp = p - off;
  int diag0 = dp * 2;
  int has2 = (diag0 + 1 <= 15 - st);
  int diag1 = has2 ? diag0 + 1 : diag0;  // clamp: singleton duplicates diag0
  int mt0 = st + diag0, mt1 = st + diag1;
  int tid = threadIdx.x, lane = tid & 63, wv = tid >> 6;
  int wm = (wv & 1) * 64, wn = (wv >> 1) * 64;
  int b0 = nt * 2;
  int ml = lane & 15, qv = lane >> 4;
  int p264 = (7 - (ml & 7)) * 264;           // phase row in Dsm
  int yb = (ml < 8 ? 120 : 112) - wm;        // y0 = s0 - x*16 + yb

  f32x4 zero = {0.f, 0.f, 0.f, 0.f};
  f32x4 acc[2][4][4];
#pragma unroll
  for (int t = 0; t < 2; ++t)
#pragma unroll
    for (int x = 0; x < 4; ++x)
#pragma unroll
      for (int y = 0; y < 4; ++y) acc[t][x][y] = zero;

  const f16* dpl0 = Dpre + (size_t)(diag0 * 24) * 2560;
  const f16* dpl1 = Dpre + (size_t)(diag1 * 24) * 2560;

#pragma unroll 1
  for (int k = 0; k < 24; ++k) {
    // stage both D tables: 320 chunks each (256 all-waves + 64 by wave 0)
    const f16* dk0 = dpl0 + k * 2560;
    const f16* dk1 = dpl1 + k * 2560;
    gl_lds16(dk0 + tid * 8, &Dsm[0][wv * 512]);
    gl_lds16(dk1 + tid * 8, &Dsm[1][wv * 512]);
    if (wv == 0) {
      gl_lds16(dk0 + (256 + lane) * 8, &Dsm[0][2048]);
      gl_lds16(dk1 + (256 + lane) * 8, &Dsm[1][2048]);
    }
    // stage B tile: 128 n-rows x 128 s (32 KB), XOR-swizzled 16B chunks
#pragma unroll
    for (int v = 0; v < 8; ++v) {
      int flat = v * 256 + tid;
      int row = flat >> 4, cl = flat & 15, cg = cl ^ (row & 15);
      int bb = b0 + (row >> 6), e = row & 63;
      gl_lds16(W2T + ((size_t)((bb * 24 + k) * 64 + e)) * 2048 + st * 128 + cg * 8,
               &Bsm[(v * 256 + wv * 64) * 8]);
    }
    __syncthreads();
#pragma unroll
    for (int ks = 0; ks < 4; ++ks) {
      int s0q = ks * 32 + qv * 8;
      f16x8 bf[4];
#pragma unroll
      for (int y = 0; y < 4; ++y) {
        int n = wn + y * 16 + ml;
        int cl = (ks * 4 + qv) ^ (n & 15);
        bf[y] = *(const f16x8*)&Bsm[n * 128 + cl * 8];
      }
      // t-sequential: bf shared across both tiles, af re-read per tile
      // (keeps live temps at af[4]+bf[4]=32 VGPR on top of 128 acc)
#pragma unroll
      for (int t = 0; t < 2; ++t) {
        f16x8 af[4];
#pragma unroll
        for (int x = 0; x < 4; ++x)
          af[x] = *(const f16x8*)&Dsm[t][p264 + s0q - x * 16 + yb];
#pragma unroll
        for (int x = 0; x < 4; ++x)
#pragma unroll
          for (int y = 0; y < 4; ++y)
            acc[t][x][y] = __builtin_amdgcn_mfma_f32_16x16x32_f16(
                af[x], bf[y], acc[t][x][y], 0, 0, 0);
      }
    }
    __syncthreads();
  }

  int n0 = nt * 128 + wn;
#pragma unroll
  for (int t = 0; t < 2; ++t) {
    if (t == 1 && !has2) break;  // singleton: discard duplicate tile
    int t0 = (t ? mt1 : mt0) * 128 + wm;
#pragma unroll
    for (int x = 0; x < 4; ++x) {
      int rbase = t0 + x * 16 + (qv << 2);
#pragma unroll
      for (int y = 0; y < 4; ++y) {
        int col = n0 + y * 16 + ml;
        int b = col >> 6, e = col & 63;
#pragma unroll
        for (int r = 0; r < 4; ++r)
          atomicAdd(&out[((size_t)(b * 2048 + rbase + r)) * 64 + e],
                    acc[t][x][y][r]);
      }
    }
  }
}

extern "C" void kernel_launch(void* const* d_in, const int* in_sizes, int n_in,
                              void* d_out, int out_size, void* d_ws, size_t ws_size,
                              hipStream_t stream) {
  const float* inputs = (const float*)d_in[0];  // [16,2048,64]
  const float* m_phi = (const float*)d_in[1];   // [1536,64]
  const float* ev = (const float*)d_in[2];      // [24]
  const float* evec = (const float*)d_in[3];    // [2048,24]
  float* out = (float*)d_out;                   // [16,2048,64] fp32
  char* ws = (char*)d_ws;
  // ws layout: Dpre 1,966,080 | phiT 196,608 | uin 4,194,304 | W2T 100,663,296
  f16* Dpre = (f16*)(ws);
  f16* phiT = (f16*)(ws + 1966080);
  f16* uin = (f16*)(ws + 2162688);
  f16* W2T = (f16*)(ws + 6356992);

  hipLaunchKernelGGL(k_pre0, dim3(728), dim3(256), 0, stream,
                     inputs, m_phi, ev, evec, phiT, uin, Dpre, out);
  hipLaunchKernelGGL(k_w, dim3(1536), dim3(256), 0, stream, uin, phiT, W2T);
  hipLaunchKernelGGL(k_main, dim3(8, 72), dim3(256), 0, stream, Dpre, W2T, out);
}

// Round 5
// 197.721 us; speedup vs baseline: 1.6074x; 1.6074x over previous
//
#include <hip/hip_runtime.h>

// B=16, L=2048, K=24, D=64
typedef _Float16 f16;
typedef _Float16 f16x4 __attribute__((ext_vector_type(4)));
typedef _Float16 f16x8 __attribute__((ext_vector_type(8)));
typedef float f32x4 __attribute__((ext_vector_type(4)));

__device__ __forceinline__ void gl_lds16(const void* g, void* l) {
  __builtin_amdgcn_global_load_lds(
      (__attribute__((address_space(1))) unsigned int*)(g),
      (__attribute__((address_space(3))) unsigned int*)(l), 16, 0, 0);
}

// ---- k_pre0: ALL independent precompute arms in launch #1 (728 blocks).
//   blk 0..255:   uin conversion (pre-swizzled f16 planes for k_w)
//   blk 256..279: phiT[k][e][d] = (f16) m_phi[(k*64+d)*64+e]
//   blk 280..663: Dpre phase-replicated Toeplitz tables
//   blk 664..727: zero out[]
__global__ __launch_bounds__(256) void k_pre0(const float* __restrict__ in,
                                              const float* __restrict__ m_phi,
                                              const float* __restrict__ ev,
                                              const float* __restrict__ evec,
                                              f16* __restrict__ phiT,
                                              f16* __restrict__ uin,
                                              f16* __restrict__ Dpre,
                                              float* __restrict__ out) {
  __shared__ float esm[256];
  int blk = blockIdx.x;
  int tid = threadIdx.x;
  if (blk < 256) {  // ---- uin conversion (one 128-s x 64-d plane per block)
    int b = blk >> 4, s0 = (blk & 15) * 128;
    f16* up = uin + (size_t)blk * 8192;
#pragma unroll
    for (int v = 0; v < 4; ++v) {
      int flat = v * 256 + tid;
      int row = flat >> 3, cl = flat & 7, cg = cl ^ (row & 7);
      const float* g = in + ((size_t)(b * 2048 + s0 + row)) * 64 + cg * 8;
      float4 u0 = *(const float4*)g;
      float4 u1 = *(const float4*)(g + 4);
      f16x8 h;
      h[0] = (f16)u0.x; h[1] = (f16)u0.y; h[2] = (f16)u0.z; h[3] = (f16)u0.w;
      h[4] = (f16)u1.x; h[5] = (f16)u1.y; h[6] = (f16)u1.z; h[7] = (f16)u1.w;
      *(f16x8*)&up[flat * 8] = h;
    }
    return;
  }
  if (blk < 280) {  // ---- phiT transpose
    int k = blk - 256;
    for (int idx = tid; idx < 4096; idx += 256) {
      int e = idx >> 6, d = idx & 63;
      phiT[k * 4096 + idx] = (f16)m_phi[(k * 64 + d) * 64 + e];
    }
    return;
  }
  if (blk < 664) {  // ---- Dpre blocks (384): D[p][y]=esm[254-p-y], pad 2560
    int a = blk - 280;
    int diag = a / 24, k = a % 24;
    float s4 = sqrtf(sqrtf(ev[k]));
    int base = diag * 128 - 127;
    if (tid < 255) {
      int v = base + tid;
      esm[tid] = (v >= 0) ? evec[v * 24 + k] * s4 : 0.0f;
    }
    __syncthreads();
    f16* plane = Dpre + (size_t)(diag * 24 + k) * 2560;
    for (int i = tid; i < 2560; i += 256) {
      float val = 0.f;
      if (i < 2112) {
        int p = i / 264, y = i - p * 264;
        int g = 254 - p - y;
        if (g >= 0) val = esm[g];
      }
      plane[i] = (f16)val;
    }
    return;
  }
  // ---- zero-out blocks: 64 blocks x 32768 floats
  float4* o = (float4*)(out + (size_t)(blk - 664) * 32768);
  float4 z4 = {0.f, 0.f, 0.f, 0.f};
#pragma unroll
  for (int i = 0; i < 32; ++i) o[i * 256 + tid] = z4;
}

// ---- k_w: W2T[b][k][e][s] = sum_d in[b][s][d] * m_phi[k*64+d][e]  (f16 out)
// [R15 proven version — unchanged]
__global__ __launch_bounds__(256) void k_w(const f16* __restrict__ uin,
                                           const f16* __restrict__ phiT,
                                           f16* __restrict__ W2T) {
  __shared__ __align__(16) f16 Ubuf[8320];
  __shared__ __align__(16) f16 Psm[64 * 64];
  int wblk = blockIdx.x;
  int s0 = (wblk & 15) * 128;
  int b = (wblk >> 4) & 15;
  int kg = wblk >> 8;  // 0..5
  int tid = threadIdx.x, lane = tid & 63, wv = tid >> 6;
  const f16* up = uin + (size_t)(wblk & 255) * 8192;
  // U stage: contiguous gl_lds (uin pre-swizzled by k_pre0)
#pragma unroll
  for (int v = 0; v < 4; ++v)
    gl_lds16(up + (size_t)(v * 256 + tid) * 8, &Ubuf[(v * 256 + wv * 64) * 8]);
  // P(k0) stage in the same vmcnt group
  {
    int k0 = kg * 4;
#pragma unroll
    for (int v = 0; v < 2; ++v) {
      int flat = v * 256 + tid;
      int row = flat >> 3, cl = flat & 7, cg = cl ^ (row & 7);
      gl_lds16(phiT + (size_t)k0 * 4096 + row * 64 + cg * 8,
               &Psm[(v * 256 + wv * 64) * 8]);
    }
  }
  __syncthreads();  // U + P0 resident
  int wm = wv * 32;
  f16x8 af[2][2];
#pragma unroll
  for (int ks = 0; ks < 2; ++ks)
#pragma unroll
    for (int x = 0; x < 2; ++x) {
      int m = wm + x * 16 + (lane & 15);
      int ch = (ks * 4 + (lane >> 4)) ^ (m & 7);
      af[ks][x] = *(const f16x8*)&Ubuf[m * 64 + ch * 8];
    }
  for (int ki = 0; ki < 4; ++ki) {
    int k = kg * 4 + ki;
    f32x4 zero = {0.f, 0.f, 0.f, 0.f};
    f32x4 acc[2][4];
#pragma unroll
    for (int x = 0; x < 2; ++x)
#pragma unroll
      for (int y = 0; y < 4; ++y) acc[x][y] = zero;
#pragma unroll
    for (int ks = 0; ks < 2; ++ks) {
      f16x8 bf[4];
#pragma unroll
      for (int y = 0; y < 4; ++y) {
        int n = y * 16 + (lane & 15);
        int ch = (ks * 4 + (lane >> 4)) ^ (n & 7);
        bf[y] = *(const f16x8*)&Psm[n * 64 + ch * 8];
      }
#pragma unroll
      for (int x = 0; x < 2; ++x)
#pragma unroll
        for (int y = 0; y < 4; ++y)
          acc[x][y] = __builtin_amdgcn_mfma_f32_16x16x32_f16(af[ks][x], bf[y], acc[x][y], 0, 0, 0);
    }
    __syncthreads();  // Psm reads + (iter0) af Ubuf reads done everywhere
    // transpose C (128 sigma x 64 e) into Ubuf as Csm[e][sigma], stride 130
#pragma unroll
    for (int x = 0; x < 2; ++x)
#pragma unroll
      for (int y = 0; y < 4; ++y) {
        int e = y * 16 + (lane & 15);
        int sg = wm + x * 16 + ((lane >> 4) << 2);
        f16x4 pk;
        pk[0] = (f16)acc[x][y][0]; pk[1] = (f16)acc[x][y][1];
        pk[2] = (f16)acc[x][y][2]; pk[3] = (f16)acc[x][y][3];
        *(f16x4*)&Ubuf[e * 130 + sg] = pk;
      }
    if (ki < 3) {  // prefetch next P (Psm safe to overwrite after sync above)
      int kn = k + 1;
#pragma unroll
      for (int v = 0; v < 2; ++v) {
        int flat = v * 256 + tid;
        int row = flat >> 3, cl = flat & 7, cg = cl ^ (row & 7);
        gl_lds16(phiT + (size_t)kn * 4096 + row * 64 + cg * 8,
                 &Psm[(v * 256 + wv * 64) * 8]);
      }
    }
    __syncthreads();  // Csm visible; P(kn) drained (implicit vmcnt(0))
    // coalesced stores: 1024 chunks of 16B; 16 lanes cover 256B of one e-row
#pragma unroll
    for (int pass = 0; pass < 4; ++pass) {
      int g = pass * 256 + tid;
      int e = g >> 4, ch = g & 15;
      f16x8 val = *(const f16x8*)&Ubuf[e * 130 + ch * 8];
      *(f16x8*)&W2T[((size_t)((b * 24 + k) * 64 + e)) * 2048 + s0 + ch * 8] = val;
    }
  }
}

// ---- k_main: causal block-Toeplitz GEMM.
// R20 "dual-diag, register-budgeted": R19 post-mortem — B-panel reuse across
// diagonals is real (FETCH 113->95 MB) but acc[2][4][4]=128 VGPR overflowed
// the (256,3) cap of ~168 => accumulator SPILLED (VGPR_Count=84, WRITE_SIZE
// 69.6->225 MB scratch traffic). Fix: halve the N-tile. Each block computes
// TWO diag tiles of 128(sigma) x 64(e) for ONE batch b: acc[2][4][2] = 64
// VGPR -> total ~110, fits __launch_bounds__(256,4) cap of 128 with NO
// spill, and 26 KB LDS (16 KB B + 10 KB D) gives 4 blocks/CU. Per-CU
// per-k-step: 1024 wave-MFMA / 104 KB staged vs R15's 768 / 111 KB = +42%
// arithmetic intensity, with MORE resident blocks (4 vs 3) for implicit
// inter-block overlap. Schedule: proven plain 2-barrier loop (R16-R18:
// source pipelining on this structure only regresses).
// Grid (16, 72): b x (st, diag-pair). Singleton pairs duplicate diag0 and
// discard the second tile (uniform work, no extra atomics).
__global__ __launch_bounds__(256, 4) void k_main(const f16* __restrict__ Dpre,
                                                 const f16* __restrict__ W2T,
                                                 float* __restrict__ out) {
  __shared__ __align__(16) f16 Bsm[64 * 128];  // 16 KB: 64 e-rows x 128 s
  __shared__ __align__(16) f16 Dsm[2][2560];   // 10 KB: two diag tables
  int b = blockIdx.x;  // 0..15
  int p = blockIdx.y;  // 0..71
  // decode p -> (st, dp): st has ceil((16-st)/2) = (17-st)>>1 pairs
  int st = 0, off = 0;
  while (off + ((17 - st) >> 1) <= p) { off += (17 - st) >> 1; ++st; }
  int dp = p - off;
  int diag0 = dp * 2;
  int has2 = (diag0 + 1 <= 15 - st);
  int diag1 = has2 ? diag0 + 1 : diag0;  // clamp: singleton duplicates diag0
  int mt0 = st + diag0, mt1 = st + diag1;
  int tid = threadIdx.x, lane = tid & 63, wv = tid >> 6;
  int wm = (wv & 1) * 64;        // M half (sigma)
  int wn = (wv >> 1) * 32;       // N quarter-pair (e)
  int ml = lane & 15, qv = lane >> 4;
  int p264 = (7 - (ml & 7)) * 264;           // phase row in Dsm
  int yb = (ml < 8 ? 120 : 112) - wm;        // y0 = s0 - x*16 + yb

  f32x4 zero = {0.f, 0.f, 0.f, 0.f};
  f32x4 acc[2][4][2];
#pragma unroll
  for (int t = 0; t < 2; ++t)
#pragma unroll
    for (int x = 0; x < 4; ++x)
#pragma unroll
      for (int y = 0; y < 2; ++y) acc[t][x][y] = zero;

  const f16* dpl0 = Dpre + (size_t)(diag0 * 24) * 2560;
  const f16* dpl1 = Dpre + (size_t)(diag1 * 24) * 2560;

#pragma unroll 1
  for (int k = 0; k < 24; ++k) {
    // stage both D tables: 320 chunks each (256 all-waves + 64 by wave 0)
    const f16* dk0 = dpl0 + k * 2560;
    const f16* dk1 = dpl1 + k * 2560;
    gl_lds16(dk0 + tid * 8, &Dsm[0][wv * 512]);
    gl_lds16(dk1 + tid * 8, &Dsm[1][wv * 512]);
    if (wv == 0) {
      gl_lds16(dk0 + (256 + lane) * 8, &Dsm[0][2048]);
      gl_lds16(dk1 + (256 + lane) * 8, &Dsm[1][2048]);
    }
    // stage B tile: 64 e-rows x 128 s (16 KB), XOR-swizzled 16B chunks
#pragma unroll
    for (int v = 0; v < 4; ++v) {
      int flat = v * 256 + tid;
      int row = flat >> 4, cl = flat & 15, cg = cl ^ (row & 15);
      gl_lds16(W2T + ((size_t)((b * 24 + k) * 64 + row)) * 2048 + st * 128 + cg * 8,
               &Bsm[(v * 256 + wv * 64) * 8]);
    }
    __syncthreads();
#pragma unroll
    for (int ks = 0; ks < 4; ++ks) {
      int s0q = ks * 32 + qv * 8;
      f16x8 bf[2];
#pragma unroll
      for (int y = 0; y < 2; ++y) {
        int n = wn + y * 16 + ml;
        int cl = (ks * 4 + qv) ^ (n & 15);
        bf[y] = *(const f16x8*)&Bsm[n * 128 + cl * 8];
      }
      // t-sequential: bf shared across both diag tiles, af re-read per tile
#pragma unroll
      for (int t = 0; t < 2; ++t) {
        f16x8 af[4];
#pragma unroll
        for (int x = 0; x < 4; ++x)
          af[x] = *(const f16x8*)&Dsm[t][p264 + s0q - x * 16 + yb];
#pragma unroll
        for (int x = 0; x < 4; ++x)
#pragma unroll
          for (int y = 0; y < 2; ++y)
            acc[t][x][y] = __builtin_amdgcn_mfma_f32_16x16x32_f16(
                af[x], bf[y], acc[t][x][y], 0, 0, 0);
      }
    }
    __syncthreads();
  }

#pragma unroll
  for (int t = 0; t < 2; ++t) {
    if (t == 1 && !has2) break;  // singleton: discard duplicate tile
    int t0 = (t ? mt1 : mt0) * 128 + wm;
#pragma unroll
    for (int x = 0; x < 4; ++x) {
      int rbase = t0 + x * 16 + (qv << 2);
#pragma unroll
      for (int y = 0; y < 2; ++y) {
        int e = wn + y * 16 + ml;
#pragma unroll
        for (int r = 0; r < 4; ++r)
          atomicAdd(&out[((size_t)(b * 2048 + rbase + r)) * 64 + e],
                    acc[t][x][y][r]);
      }
    }
  }
}

extern "C" void kernel_launch(void* const* d_in, const int* in_sizes, int n_in,
                              void* d_out, int out_size, void* d_ws, size_t ws_size,
                              hipStream_t stream) {
  const float* inputs = (const float*)d_in[0];  // [16,2048,64]
  const float* m_phi = (const float*)d_in[1];   // [1536,64]
  const float* ev = (const float*)d_in[2];      // [24]
  const float* evec = (const float*)d_in[3];    // [2048,24]
  float* out = (float*)d_out;                   // [16,2048,64] fp32
  char* ws = (char*)d_ws;
  // ws layout: Dpre 1,966,080 | phiT 196,608 | uin 4,194,304 | W2T 100,663,296
  f16* Dpre = (f16*)(ws);
  f16* phiT = (f16*)(ws + 1966080);
  f16* uin = (f16*)(ws + 2162688);
  f16* W2T = (f16*)(ws + 6356992);

  hipLaunchKernelGGL(k_pre0, dim3(728), dim3(256), 0, stream,
                     inputs, m_phi, ev, evec, phiT, uin, Dpre, out);
  hipLaunchKernelGGL(k_w, dim3(1536), dim3(256), 0, stream, uin, phiT, W2T);
  hipLaunchKernelGGL(k_main, dim3(16, 72), dim3(256), 0, stream, Dpre, W2T, out);
}